// Round 5
// baseline (1472.874 us; speedup 1.0000x reference)
//
#include <hip/hip_runtime.h>
#include <cstdint>

#define DF 128

typedef float f32x4 __attribute__((ext_vector_type(4)));
typedef short bf16x8 __attribute__((ext_vector_type(8)));

__device__ __forceinline__ unsigned short f2bf(float f) {
  unsigned int u = __float_as_uint(f);
  return (unsigned short)((u + 0x7fffu + ((u >> 16) & 1u)) >> 16);
}
__device__ __forceinline__ unsigned int pack2(float lo, float hi) {
  return (unsigned int)f2bf(lo) | ((unsigned int)f2bf(hi) << 16);
}
__device__ __forceinline__ float bflo(unsigned int u) { return __uint_as_float(u << 16); }
__device__ __forceinline__ float bfhi(unsigned int u) { return __uint_as_float(u & 0xffff0000u); }

// ---- W concat+convert: wbf[c][k] bf16, k<128 -> Wl[c][k], k>=128 -> Wr[c][k-128]
__global__ void k_wcvt(const float* __restrict__ Wl, const float* __restrict__ Wr,
                       unsigned short* __restrict__ wbf) {
  int i = blockIdx.x * 256 + threadIdx.x;  // 0..32767
  int c = i >> 8;
  int k = i & 255;
  float v = (k < DF) ? Wl[c * DF + k] : Wr[c * DF + (k - DF)];
  wbf[i] = f2bf(v);
}

// ---- x -> bf16 copy (8 elems/thread)
__global__ void k_xcvt(const float* __restrict__ x, unsigned int* __restrict__ xbf, int total8) {
  int i = blockIdx.x * 256 + threadIdx.x;
  if (i >= total8) return;
  const float4* xr = (const float4*)(x + (size_t)i * 8);
  float4 a = xr[0], b = xr[1];
  uint4 v;
  v.x = pack2(a.x, a.y);
  v.y = pack2(a.z, a.w);
  v.z = pack2(b.x, b.y);
  v.w = pack2(b.z, b.w);
  ((uint4*)xbf)[i] = v;
}

// ---- per-block bucket histogram (bucket = dst>>6), NO global atomics
__global__ __launch_bounds__(256) void k_hist(const int* __restrict__ ei,
                                              unsigned int* __restrict__ hist,
                                              int E, int NBK, int CE) {
  __shared__ unsigned int h[4096];
  for (int i = threadIdx.x; i < NBK; i += 256) h[i] = 0u;
  __syncthreads();
  int b0 = blockIdx.x * CE;
  int b1 = b0 + CE < E ? b0 + CE : E;
  for (int e = b0 + threadIdx.x; e < b1; e += 256)
    atomicAdd(&h[((unsigned int)ei[(size_t)E + e]) >> 6], 1u);
  __syncthreads();
  for (int i = threadIdx.x; i < NBK; i += 256)
    hist[(size_t)blockIdx.x * NBK + i] = h[i];
}

// ---- bucket totals: tot[j] = sum_b hist[b][j]
__global__ void k_btot(const unsigned int* __restrict__ hist, unsigned int* __restrict__ tot,
                       int NBK, int NBLK) {
  int j = blockIdx.x * 256 + threadIdx.x;
  if (j >= NBK) return;
  unsigned int s = 0u;
  for (int b = 0; b < NBLK; ++b) s += hist[(size_t)b * NBK + j];
  tot[j] = s;
}

// ---- exclusive scan of bucket totals (1 block); bstart[NBK] = E
__global__ __launch_bounds__(256) void k_scan(const unsigned int* __restrict__ tot,
                                              unsigned int* __restrict__ bstart,
                                              int NBK, int CHK) {
  __shared__ unsigned int sums[256];
  int t = threadIdx.x;
  unsigned int loc[16];
  unsigned int s = 0u;
#pragma unroll
  for (int k = 0; k < 16; ++k) {
    if (k < CHK) {
      int j = t * CHK + k;
      loc[k] = s;
      s += (j < NBK) ? tot[j] : 0u;
    }
  }
  sums[t] = s;
  __syncthreads();
  for (int off = 1; off < 256; off <<= 1) {
    unsigned int a = (t >= off) ? sums[t - off] : 0u;
    __syncthreads();
    sums[t] += a;
    __syncthreads();
  }
  unsigned int basev = (t > 0) ? sums[t - 1] : 0u;
#pragma unroll
  for (int k = 0; k < 16; ++k) {
    if (k < CHK) {
      int j = t * CHK + k;
      if (j < NBK) bstart[j] = basev + loc[k];
    }
  }
  if (t == 255) bstart[NBK] = sums[255];
}

// ---- per-(block,bucket) write cursors: base[b][j] = bstart[j] + sum_{b'<b} hist[b'][j]
__global__ void k_base(const unsigned int* __restrict__ hist,
                       const unsigned int* __restrict__ bstart,
                       unsigned int* __restrict__ base, int NBK, int NBLK) {
  int j = blockIdx.x * 256 + threadIdx.x;
  if (j >= NBK) return;
  unsigned int run = bstart[j];
  for (int b = 0; b < NBLK; ++b) {
    base[(size_t)b * NBK + j] = run;
    run += hist[(size_t)b * NBK + j];
  }
}

// ---- scatter edges into bucket segments (LDS cursors only)
__global__ __launch_bounds__(256) void k_scat(const int* __restrict__ ei,
                                              const unsigned int* __restrict__ base,
                                              unsigned int* __restrict__ ebuf,
                                              int E, int NBK, int CE) {
  __shared__ unsigned int cur[4096];
  for (int i = threadIdx.x; i < NBK; i += 256)
    cur[i] = base[(size_t)blockIdx.x * NBK + i];
  __syncthreads();
  int b0 = blockIdx.x * CE;
  int b1 = b0 + CE < E ? b0 + CE : E;
  for (int e = b0 + threadIdx.x; e < b1; e += 256) {
    unsigned int s = (unsigned int)ei[e];
    unsigned int t = (unsigned int)ei[(size_t)E + e];
    unsigned int p = atomicAdd(&cur[t >> 6], 1u);
    ebuf[p] = (s << 6) | (t & 63u);
  }
}

// ---- fused: bucket aggregation (LDS) + GEMM + row L2 norm + per-block partials
// block b owns nodes [64b, 64b+64) == bucket b
template <int XBF>
__global__ __launch_bounds__(256) void k_gemm(
    const unsigned int* __restrict__ ebuf, const unsigned int* __restrict__ bstart,
    const unsigned int* __restrict__ xb, const float* __restrict__ x,
    const unsigned short* __restrict__ wbf, const float* __restrict__ bl,
    float* __restrict__ hout, float* __restrict__ pf, int n) {
  __shared__ __align__(16) char smem[49408];
  float* aggF = (float*)smem;                              // 32 KB (64 nodes x 128 f32)
  unsigned short* Bbuf = (unsigned short*)smem;            // alias (after agg consumed)
  unsigned short* Abuf = (unsigned short*)(smem + 32768);  // 16 KB
  unsigned int* degS = (unsigned int*)(smem + 49152);      // 256 B
  float* red = (float*)(smem + 32768);                     // alias of Abuf for epilogue

  int tid = threadIdx.x;
  int node0 = blockIdx.x * 64;
  int wv = tid >> 6, lane = tid & 63;
  int lo = lane & 15, hi = lane >> 4;

  // zero accumulators
  {
    float4 z = make_float4(0.f, 0.f, 0.f, 0.f);
    float4* az = (float4*)aggF;
    for (int i = tid; i < 2048; i += 256) az[i] = z;
    if (tid < 64) degS[tid] = 0u;
  }
  __syncthreads();

  // ---- gather-aggregate this bucket's edges
  int segStart = (int)bstart[blockIdx.x];
  int L = (int)bstart[blockIdx.x + 1] - segStart;
  int nfull = L >> 6;
  const float2* x2 = (const float2*)x;
  for (int c = wv; c < nfull; c += 4) {
    int basee = segStart + (c << 6);
    unsigned int ent = ebuf[basee + lane];
    atomicAdd(&degS[ent & 63u], 1u);
    for (int j0 = 0; j0 < 64; j0 += 8) {
      int dl[8];
      unsigned int rr[8];
      float2 ff[8];
#pragma unroll
      for (int k2 = 0; k2 < 8; ++k2) {
        unsigned int u = __shfl(ent, j0 + k2, 64);
        dl[k2] = (int)(u & 63u);
        if (XBF) rr[k2] = xb[(size_t)(u >> 6) * 64 + lane];
        else ff[k2] = x2[(size_t)(u >> 6) * 64 + lane];
      }
#pragma unroll
      for (int k2 = 0; k2 < 8; ++k2) {
        float a0 = XBF ? bflo(rr[k2]) : ff[k2].x;
        float a1 = XBF ? bfhi(rr[k2]) : ff[k2].y;
        atomicAdd(&aggF[dl[k2] * 128 + lane * 2], a0);
        atomicAdd(&aggF[dl[k2] * 128 + lane * 2 + 1], a1);
      }
    }
  }
  int trem = L & 63;
  if (trem && wv == (nfull & 3)) {
    int basee = segStart + (nfull << 6);
    unsigned int ent = 0u;
    if (lane < trem) {
      ent = ebuf[basee + lane];
      atomicAdd(&degS[ent & 63u], 1u);
    }
    for (int j0 = 0; j0 < trem; j0 += 8) {
      int dl[8];
      unsigned int rr[8];
      float2 ff[8];
#pragma unroll
      for (int k2 = 0; k2 < 8; ++k2) {
        if (j0 + k2 < trem) {
          unsigned int u = __shfl(ent, j0 + k2, 64);
          dl[k2] = (int)(u & 63u);
          if (XBF) rr[k2] = xb[(size_t)(u >> 6) * 64 + lane];
          else ff[k2] = x2[(size_t)(u >> 6) * 64 + lane];
        }
      }
#pragma unroll
      for (int k2 = 0; k2 < 8; ++k2) {
        if (j0 + k2 < trem) {
          float a0 = XBF ? bflo(rr[k2]) : ff[k2].x;
          float a1 = XBF ? bfhi(rr[k2]) : ff[k2].y;
          atomicAdd(&aggF[dl[k2] * 128 + lane * 2], a0);
          atomicAdd(&aggF[dl[k2] * 128 + lane * 2 + 1], a1);
        }
      }
    }
  }
  __syncthreads();

  // ---- convert agg -> swizzled bf16 A-tile (mean via 1/max(deg,1))
  for (int c = tid; c < 1024; c += 256) {
    int row = c >> 4;
    int part = c & 15;
    unsigned int d = degS[row];
    float inv = 1.0f / (float)(d > 1u ? d : 1u);
    const float* s = &aggF[row * 128 + part * 8];
    uint4 v;
    v.x = pack2(s[0] * inv, s[1] * inv);
    v.y = pack2(s[2] * inv, s[3] * inv);
    v.z = pack2(s[4] * inv, s[5] * inv);
    v.w = pack2(s[6] * inv, s[7] * inv);
    *(uint4*)((char*)Abuf + ((row * 256 + part * 16) ^ ((row & 7) << 4))) = v;
  }
  __syncthreads();  // aggF fully consumed; Bbuf may now overwrite it

  f32x4 acc[8] = {};
  int arow = wv * 16 + lo;
  int abase = arow * 256 + hi * 16;
  int aswz = (arow & 7) << 4;

  for (int ph = 0; ph < 2; ++ph) {
    if (ph) {
      __syncthreads();
      // stage A half-tile from x (rows of the block), bf16 swizzled
#pragma unroll
      for (int it = 0; it < 4; ++it) {
        int id = it * 256 + tid;
        int row = id >> 4;
        int inner = (id & 15) * 16;
        uint4 v = make_uint4(0u, 0u, 0u, 0u);
        int gr = node0 + row;
        if (gr < n) {
          if (XBF) {
            v = *(const uint4*)((const unsigned short*)xb + (size_t)gr * DF + inner / 2);
          } else {
            const float4* xr = (const float4*)(x + (size_t)gr * DF + inner / 2);
            float4 a = xr[0], b = xr[1];
            v.x = pack2(a.x, a.y);
            v.y = pack2(a.z, a.w);
            v.z = pack2(b.x, b.y);
            v.w = pack2(b.z, b.w);
          }
        }
        *(uint4*)((char*)Abuf + ((row * 256 + inner) ^ ((row & 7) << 4))) = v;
      }
    }
    // stage B half-tile: 128 cols x 128 k
#pragma unroll
    for (int it = 0; it < 8; ++it) {
      int id = it * 256 + tid;
      int cC = id >> 4;
      int inner = (id & 15) * 16;
      uint4 v = *(const uint4*)((const char*)wbf + (size_t)cC * 512 + ph * 256 + inner);
      *(uint4*)((char*)Bbuf + ((cC * 256 + inner) ^ ((cC & 7) << 4))) = v;
    }
    __syncthreads();
#pragma unroll
    for (int kk = 0; kk < 4; ++kk) {
      bf16x8 af = *(const bf16x8*)((const char*)Abuf + ((abase + kk * 64) ^ aswz));
#pragma unroll
      for (int f = 0; f < 8; ++f) {
        int brow = f * 16 + lo;
        int bb = (brow * 256 + hi * 16 + kk * 64) ^ ((brow & 7) << 4);
        bf16x8 bfr = *(const bf16x8*)((const char*)Bbuf + bb);
        acc[f] = __builtin_amdgcn_mfma_f32_16x16x32_bf16(af, bfr, acc[f], 0, 0, 0);
      }
    }
  }

  // ---- epilogue: bias, guard pad rows, row L2 norm, store h, feature partials
  int r0 = node0 + wv * 16 + hi * 4;
#pragma unroll
  for (int f = 0; f < 8; ++f) {
    float b = bl[f * 16 + lo];
#pragma unroll
    for (int r = 0; r < 4; ++r) acc[f][r] += b;
  }
#pragma unroll
  for (int r = 0; r < 4; ++r) {
    if (r0 + r >= n) {
#pragma unroll
      for (int f = 0; f < 8; ++f) acc[f][r] = 0.f;
    }
  }
  float ss[4] = {0.f, 0.f, 0.f, 0.f};
#pragma unroll
  for (int f = 0; f < 8; ++f)
#pragma unroll
    for (int r = 0; r < 4; ++r) ss[r] += acc[f][r] * acc[f][r];
#pragma unroll
  for (int m = 1; m <= 8; m <<= 1) {
#pragma unroll
    for (int r = 0; r < 4; ++r) ss[r] += __shfl_xor(ss[r], m, 64);
  }
#pragma unroll
  for (int r = 0; r < 4; ++r) {
    float inv = 1.0f / fmaxf(sqrtf(ss[r]), 1e-12f);
#pragma unroll
    for (int f = 0; f < 8; ++f) acc[f][r] *= inv;
  }
  float s1[8], s2[8];
#pragma unroll
  for (int f = 0; f < 8; ++f) { s1[f] = 0.f; s2[f] = 0.f; }
#pragma unroll
  for (int f = 0; f < 8; ++f) {
#pragma unroll
    for (int r = 0; r < 4; ++r) {
      float v = acc[f][r];
      s1[f] += v;
      s2[f] += v * v;
      if (r0 + r < n) hout[(size_t)(r0 + r) * DF + f * 16 + lo] = v;
    }
  }
#pragma unroll
  for (int f = 0; f < 8; ++f) {
    s1[f] += __shfl_xor(s1[f], 16, 64);
    s1[f] += __shfl_xor(s1[f], 32, 64);
    s2[f] += __shfl_xor(s2[f], 16, 64);
    s2[f] += __shfl_xor(s2[f], 32, 64);
  }
  __syncthreads();  // done with Abuf/Bbuf reads
  if (hi == 0) {
#pragma unroll
    for (int f = 0; f < 8; ++f) {
      red[wv * 256 + f * 16 + lo] = s1[f];
      red[wv * 256 + 128 + f * 16 + lo] = s2[f];
    }
  }
  __syncthreads();
  float v = red[tid] + red[256 + tid] + red[512 + tid] + red[768 + tid];
  pf[(size_t)blockIdx.x * 256 + tid] = v;
}

// ---- first-level partial reduction: 16 blocks x 256 feats (coalesced)
__global__ void k_reduce(const float* __restrict__ pf, float* __restrict__ pf2, int NB) {
  int g = blockIdx.x, t = threadIdx.x;
  int L = (NB + 15) / 16;
  int b0 = g * L, b1 = (b0 + L < NB) ? b0 + L : NB;
  float a = 0.f;
  for (int r = b0; r < b1; ++r) a += pf[(size_t)r * 256 + t];
  pf2[g * 256 + t] = a;
}

// ---- GraphNorm coefficients: out = ca*h + cb per feature
__global__ void k_coef(const float* __restrict__ pf2,
                       const float* __restrict__ gnw, const float* __restrict__ gnb,
                       const float* __restrict__ alpha, float* __restrict__ coef, int n) {
  int j = threadIdx.x;  // 0..127
  float s = 0.f, q = 0.f;
#pragma unroll
  for (int g = 0; g < 16; ++g) {
    s += pf2[g * 256 + j];
    q += pf2[g * 256 + 128 + j];
  }
  float invn = 1.0f / (float)n;
  float mean = s * invn;
  float m2 = q * invn;
  float a = alpha[j];
  float var = m2 - mean * mean * (2.0f * a - a * a);
  float ca = gnw[j] / sqrtf(var + 1e-5f);
  float cb = gnb[j] - ca * a * mean;
  coef[j] = ca;
  coef[DF + j] = cb;
}

// ---- affine + exact GELU + residual, in-place on d_out
__global__ void k_final(float* __restrict__ out, const float* __restrict__ x,
                        const float* __restrict__ coef, int total4) {
  int i = blockIdx.x * 256 + threadIdx.x;
  if (i >= total4) return;
  int cj = (i & 31) * 4;
  float4 h = ((const float4*)out)[i];
  float4 xv = ((const float4*)x)[i];
  float4 ca = *(const float4*)(coef + cj);
  float4 cb = *(const float4*)(coef + DF + cj);
  float4 o;
#define GEL(comp)                                                         \
  {                                                                       \
    float v = ca.comp * h.comp + cb.comp;                                 \
    float g = 0.5f * v * (1.0f + erff(v * 0.70710678118654752f));         \
    o.comp = g + xv.comp;                                                 \
  }
  GEL(x) GEL(y) GEL(z) GEL(w)
#undef GEL
  ((float4*)out)[i] = o;
}

extern "C" void kernel_launch(void* const* d_in, const int* in_sizes, int n_in,
                              void* d_out, int out_size, void* d_ws, size_t ws_size,
                              hipStream_t stream) {
  const float* x = (const float*)d_in[0];
  const int* ei = (const int*)d_in[1];
  // d_in[2] = batch (all zeros, unused)
  const float* Wl = (const float*)d_in[3];
  const float* bl = (const float*)d_in[4];
  const float* Wr = (const float*)d_in[5];
  const float* gnw = (const float*)d_in[6];
  const float* gnb = (const float*)d_in[7];
  const float* alpha = (const float*)d_in[8];
  int n = in_sizes[2];
  int E = in_sizes[1] / 2;
  int NBK = (n + 63) / 64;        // buckets == gemm blocks
  const int NBLK = 128;           // hist/scatter blocks
  int CE = (E + NBLK - 1) / NBLK;
  int CHK = (NBK + 255) / 256;    // <=16 for n<=262144
  float* out = (float*)d_out;
  (void)n_in; (void)out_size;

  char* ws = (char*)d_ws;
  size_t off = 0;
  auto carve = [&](size_t b) {
    char* p = ws + off;
    off = (off + b + 255) & ~(size_t)255;
    return p;
  };
  unsigned int* ebuf = (unsigned int*)carve((size_t)E * 4);
  unsigned int* hist = (unsigned int*)carve((size_t)NBLK * NBK * 4);
  unsigned int* base = (unsigned int*)carve((size_t)NBLK * NBK * 4);
  unsigned int* tot = (unsigned int*)carve((size_t)NBK * 4);
  unsigned int* bstart = (unsigned int*)carve((size_t)(NBK + 1) * 4);
  unsigned short* wbf = (unsigned short*)carve((size_t)DF * 256 * 2);
  float* coef = (float*)carve(256 * 4);
  float* pf = (float*)carve((size_t)NBK * 256 * 4);
  float* pf2 = (float*)carve(16 * 256 * 4);
  size_t need_bf = off + (size_t)n * DF * 2;
  int useBF = (ws_size >= need_bf) ? 1 : 0;
  unsigned int* xbf = (unsigned int*)carve((size_t)n * DF * 2);

  k_wcvt<<<(DF * 256) / 256, 256, 0, stream>>>(Wl, Wr, wbf);
  k_hist<<<NBLK, 256, 0, stream>>>(ei, hist, E, NBK, CE);
  k_btot<<<(NBK + 255) / 256, 256, 0, stream>>>(hist, tot, NBK, NBLK);
  k_scan<<<1, 256, 0, stream>>>(tot, bstart, NBK, CHK);
  k_base<<<(NBK + 255) / 256, 256, 0, stream>>>(hist, bstart, base, NBK, NBLK);
  k_scat<<<NBLK, 256, 0, stream>>>(ei, base, ebuf, E, NBK, CE);
  if (useBF) {
    k_xcvt<<<(n * 16 + 255) / 256, 256, 0, stream>>>(x, xbf, n * 16);
    k_gemm<1><<<NBK, 256, 0, stream>>>(ebuf, bstart, xbf, x, wbf, bl, out, pf, n);
  } else {
    k_gemm<0><<<NBK, 256, 0, stream>>>(ebuf, bstart, xbf, x, wbf, bl, out, pf, n);
  }
  k_reduce<<<16, 256, 0, stream>>>(pf, pf2, NBK);
  k_coef<<<1, DF, 0, stream>>>(pf2, gnw, gnb, alpha, coef, n);
  k_final<<<(n * 32 + 255) / 256, 256, 0, stream>>>(out, x, coef, n * 32);
}

// Round 8
// 382.644 us; speedup vs baseline: 3.8492x; 3.8492x over previous
//
#include <hip/hip_runtime.h>
#include <cstdint>

#define DF 128

typedef float f32x4 __attribute__((ext_vector_type(4)));
typedef short bf16x8 __attribute__((ext_vector_type(8)));

__device__ __forceinline__ unsigned short f2bf(float f) {
  unsigned int u = __float_as_uint(f);
  return (unsigned short)((u + 0x7fffu + ((u >> 16) & 1u)) >> 16);
}
__device__ __forceinline__ unsigned int pack2(float lo, float hi) {
  return (unsigned int)f2bf(lo) | ((unsigned int)f2bf(hi) << 16);
}
__device__ __forceinline__ float bflo(unsigned int u) { return __uint_as_float(u << 16); }
__device__ __forceinline__ float bfhi(unsigned int u) { return __uint_as_float(u & 0xffff0000u); }

// ---- W concat+convert: wbf[c][k] bf16, k<128 -> Wl[c][k], k>=128 -> Wr[c][k-128]
__global__ void k_wcvt(const float* __restrict__ Wl, const float* __restrict__ Wr,
                       unsigned short* __restrict__ wbf) {
  int i = blockIdx.x * 256 + threadIdx.x;  // 0..32767
  int c = i >> 8;
  int k = i & 255;
  float v = (k < DF) ? Wl[c * DF + k] : Wr[c * DF + (k - DF)];
  wbf[i] = f2bf(v);
}

// ---- x -> bf16 copy (8 elems/thread)
__global__ void k_xcvt(const float* __restrict__ x, unsigned int* __restrict__ xbf, int total8) {
  int i = blockIdx.x * 256 + threadIdx.x;
  if (i >= total8) return;
  const float4* xr = (const float4*)(x + (size_t)i * 8);
  float4 a = xr[0], b = xr[1];
  uint4 v;
  v.x = pack2(a.x, a.y);
  v.y = pack2(a.z, a.w);
  v.z = pack2(b.x, b.y);
  v.w = pack2(b.z, b.w);
  ((uint4*)xbf)[i] = v;
}

// ---- per-block bucket histogram (bucket = dst>>6), NO global atomics
__global__ __launch_bounds__(256) void k_hist(const int* __restrict__ ei,
                                              unsigned int* __restrict__ hist,
                                              int E, int NBK, int CE) {
  __shared__ unsigned int h[4096];
  for (int i = threadIdx.x; i < NBK; i += 256) h[i] = 0u;
  __syncthreads();
  int b0 = blockIdx.x * CE;
  int b1 = b0 + CE < E ? b0 + CE : E;
  for (int e = b0 + threadIdx.x; e < b1; e += 256)
    atomicAdd(&h[((unsigned int)ei[(size_t)E + e]) >> 6], 1u);
  __syncthreads();
  for (int i = threadIdx.x; i < NBK; i += 256)
    hist[(size_t)blockIdx.x * NBK + i] = h[i];
}

// ---- bucket totals: tot[j] = sum_b hist[b][j]
__global__ void k_btot(const unsigned int* __restrict__ hist, unsigned int* __restrict__ tot,
                       int NBK, int NBLK) {
  int j = blockIdx.x * 256 + threadIdx.x;
  if (j >= NBK) return;
  unsigned int s = 0u;
  for (int b = 0; b < NBLK; ++b) s += hist[(size_t)b * NBK + j];
  tot[j] = s;
}

// ---- exclusive scan of bucket totals (1 block); bstart[NBK] = E
__global__ __launch_bounds__(256) void k_scan(const unsigned int* __restrict__ tot,
                                              unsigned int* __restrict__ bstart,
                                              int NBK, int CHK) {
  __shared__ unsigned int sums[256];
  int t = threadIdx.x;
  unsigned int loc[16];
  unsigned int s = 0u;
#pragma unroll
  for (int k = 0; k < 16; ++k) {
    if (k < CHK) {
      int j = t * CHK + k;
      loc[k] = s;
      s += (j < NBK) ? tot[j] : 0u;
    }
  }
  sums[t] = s;
  __syncthreads();
  for (int off = 1; off < 256; off <<= 1) {
    unsigned int a = (t >= off) ? sums[t - off] : 0u;
    __syncthreads();
    sums[t] += a;
    __syncthreads();
  }
  unsigned int basev = (t > 0) ? sums[t - 1] : 0u;
#pragma unroll
  for (int k = 0; k < 16; ++k) {
    if (k < CHK) {
      int j = t * CHK + k;
      if (j < NBK) bstart[j] = basev + loc[k];
    }
  }
  if (t == 255) bstart[NBK] = sums[255];
}

// ---- per-(block,bucket) write cursors: base[b][j] = bstart[j] + sum_{b'<b} hist[b'][j]
__global__ void k_base(const unsigned int* __restrict__ hist,
                       const unsigned int* __restrict__ bstart,
                       unsigned int* __restrict__ base, int NBK, int NBLK) {
  int j = blockIdx.x * 256 + threadIdx.x;
  if (j >= NBK) return;
  unsigned int run = bstart[j];
  for (int b = 0; b < NBLK; ++b) {
    base[(size_t)b * NBK + j] = run;
    run += hist[(size_t)b * NBK + j];
  }
}

// ---- scatter edges into bucket segments (LDS cursors only)
__global__ __launch_bounds__(256) void k_scat(const int* __restrict__ ei,
                                              const unsigned int* __restrict__ base,
                                              unsigned int* __restrict__ ebuf,
                                              int E, int NBK, int CE) {
  __shared__ unsigned int cur[4096];
  for (int i = threadIdx.x; i < NBK; i += 256)
    cur[i] = base[(size_t)blockIdx.x * NBK + i];
  __syncthreads();
  int b0 = blockIdx.x * CE;
  int b1 = b0 + CE < E ? b0 + CE : E;
  for (int e = b0 + threadIdx.x; e < b1; e += 256) {
    unsigned int s = (unsigned int)ei[e];
    unsigned int t = (unsigned int)ei[(size_t)E + e];
    unsigned int p = atomicAdd(&cur[t >> 6], 1u);
    ebuf[p] = (s << 6) | (t & 63u);
  }
}

// ---- fused: in-LDS counting sort + register aggregation + GEMM + L2 norm + partials
// block b owns nodes [64b, 64b+64) == bucket b
template <int XBF>
__global__ __launch_bounds__(256) void k_gemm(
    const unsigned int* __restrict__ ebuf, const unsigned int* __restrict__ bstart,
    const unsigned int* __restrict__ xb, const float* __restrict__ x,
    const unsigned short* __restrict__ wbf, const float* __restrict__ bl,
    float* __restrict__ hout, float* __restrict__ pf, int n) {
  __shared__ __align__(16) char smem[50176];
  unsigned int* sortedS = (unsigned int*)smem;             // 8192 entries (32 KB), later Bbuf
  unsigned short* Bbuf = (unsigned short*)smem;            // 32 KB
  unsigned short* Abuf = (unsigned short*)(smem + 32768);  // 16 KB
  float* red = (float*)(smem + 32768);                     // alias of Abuf for epilogue
  unsigned int* cntS = (unsigned int*)(smem + 49152);      // 64
  unsigned int* startS = (unsigned int*)(smem + 49408);    // 65
  unsigned int* curS = (unsigned int*)(smem + 49680);      // 64

  int tid = threadIdx.x;
  int node0 = blockIdx.x * 64;
  int wv = tid >> 6, lane = tid & 63;
  int lo = lane & 15, hi = lane >> 4;

  int segStart = (int)bstart[blockIdx.x];
  int L = (int)(bstart[blockIdx.x + 1] - bstart[blockIdx.x]);

  float2 nacc[16];
  int dreg[16];
#pragma unroll
  for (int i = 0; i < 16; ++i) {
    nacc[i] = make_float2(0.f, 0.f);
    dreg[i] = 0;
  }

  const int CH = 8192;
  const float2* x2 = (const float2*)x;
  for (int c0 = 0; c0 < L; c0 += CH) {
    int cl = (L - c0 < CH) ? (L - c0) : CH;
    if (tid < 64) cntS[tid] = 0u;
    __syncthreads();
    // pass 1: count per dstLow
    for (int t = tid; t < cl; t += 256)
      atomicAdd(&cntS[ebuf[segStart + c0 + t] & 63u], 1u);
    __syncthreads();
    // scan (wave 0): startS[m] exclusive, curS[m] write cursor
    if (tid < 64) {
      unsigned int v = cntS[tid];
      unsigned int inc = v;
#pragma unroll
      for (int o = 1; o < 64; o <<= 1) {
        unsigned int t2 = __shfl_up(inc, o, 64);
        if (lane >= o) inc += t2;
      }
      startS[tid + 1] = inc;
      if (tid == 0) startS[0] = 0u;
      curS[tid] = inc - v;
    }
    __syncthreads();
    // pass 2: place src ids grouped by dstLow
    for (int t = tid; t < cl; t += 256) {
      unsigned int u = ebuf[segStart + c0 + t];
      unsigned int p = atomicAdd(&curS[u & 63u], 1u);
      sortedS[p] = u >> 6;
    }
    __syncthreads();
    // aggregate: wave wv owns nodes wv*16..wv*16+15, register accumulation
    for (int mi = 0; mi < 16; ++mi) {
      int m = wv * 16 + mi;
      int st = (int)startS[m];
      int cn = (int)(startS[m + 1] - startS[m]);
      dreg[mi] += cn;
      float ax = nacc[mi].x, ay = nacc[mi].y;
      int j = 0;
      for (; j + 4 <= cn; j += 4) {
        unsigned int i0 = sortedS[st + j], i1 = sortedS[st + j + 1],
                     i2 = sortedS[st + j + 2], i3 = sortedS[st + j + 3];
        if (XBF) {
          unsigned int u0 = xb[(size_t)i0 * 64 + lane], u1 = xb[(size_t)i1 * 64 + lane],
                       u2 = xb[(size_t)i2 * 64 + lane], u3 = xb[(size_t)i3 * 64 + lane];
          ax += bflo(u0) + bflo(u1) + bflo(u2) + bflo(u3);
          ay += bfhi(u0) + bfhi(u1) + bfhi(u2) + bfhi(u3);
        } else {
          float2 v0 = x2[(size_t)i0 * 64 + lane], v1 = x2[(size_t)i1 * 64 + lane],
                 v2 = x2[(size_t)i2 * 64 + lane], v3 = x2[(size_t)i3 * 64 + lane];
          ax += v0.x + v1.x + v2.x + v3.x;
          ay += v0.y + v1.y + v2.y + v3.y;
        }
      }
      for (; j < cn; ++j) {
        unsigned int i0 = sortedS[st + j];
        if (XBF) {
          unsigned int u0 = xb[(size_t)i0 * 64 + lane];
          ax += bflo(u0);
          ay += bfhi(u0);
        } else {
          float2 v = x2[(size_t)i0 * 64 + lane];
          ax += v.x;
          ay += v.y;
        }
      }
      nacc[mi].x = ax;
      nacc[mi].y = ay;
    }
    __syncthreads();  // all waves done with sortedS before next chunk
  }

  // ---- write agg A-tile (mean), swizzled bf16
#pragma unroll
  for (int mi = 0; mi < 16; ++mi) {
    int row = wv * 16 + mi;
    int d = dreg[mi];
    float inv = 1.0f / (float)(d > 1 ? d : 1);
    unsigned int pr = pack2(nacc[mi].x * inv, nacc[mi].y * inv);
    *(unsigned int*)((char*)Abuf + ((row * 256 + lane * 4) ^ ((row & 7) << 4))) = pr;
  }
  __syncthreads();  // agg reads done; Bbuf region may be overwritten

  f32x4 acc[8] = {};
  int arow = wv * 16 + lo;
  int abase = arow * 256 + hi * 16;
  int aswz = (arow & 7) << 4;

  for (int ph = 0; ph < 2; ++ph) {
    if (ph) {
      __syncthreads();
      // stage A half-tile from x rows, bf16 swizzled
#pragma unroll
      for (int it = 0; it < 4; ++it) {
        int id = it * 256 + tid;
        int row = id >> 4;
        int inner = (id & 15) * 16;
        uint4 v = make_uint4(0u, 0u, 0u, 0u);
        int gr = node0 + row;
        if (gr < n) {
          if (XBF) {
            v = *(const uint4*)((const unsigned short*)xb + (size_t)gr * DF + inner / 2);
          } else {
            const float4* xr = (const float4*)(x + (size_t)gr * DF + inner / 2);
            float4 a = xr[0], b = xr[1];
            v.x = pack2(a.x, a.y);
            v.y = pack2(a.z, a.w);
            v.z = pack2(b.x, b.y);
            v.w = pack2(b.z, b.w);
          }
        }
        *(uint4*)((char*)Abuf + ((row * 256 + inner) ^ ((row & 7) << 4))) = v;
      }
    }
    // stage B half-tile: 128 cols x 128 k
#pragma unroll
    for (int it = 0; it < 8; ++it) {
      int id = it * 256 + tid;
      int cC = id >> 4;
      int inner = (id & 15) * 16;
      uint4 v = *(const uint4*)((const char*)wbf + (size_t)cC * 512 + ph * 256 + inner);
      *(uint4*)((char*)Bbuf + ((cC * 256 + inner) ^ ((cC & 7) << 4))) = v;
    }
    __syncthreads();
#pragma unroll
    for (int kk = 0; kk < 4; ++kk) {
      bf16x8 af = *(const bf16x8*)((const char*)Abuf + ((abase + kk * 64) ^ aswz));
#pragma unroll
      for (int f = 0; f < 8; ++f) {
        int brow = f * 16 + lo;
        int bb = (brow * 256 + hi * 16 + kk * 64) ^ ((brow & 7) << 4);
        bf16x8 bfr = *(const bf16x8*)((const char*)Bbuf + bb);
        acc[f] = __builtin_amdgcn_mfma_f32_16x16x32_bf16(af, bfr, acc[f], 0, 0, 0);
      }
    }
  }

  // ---- epilogue: bias, guard pad rows, row L2 norm, store h, feature partials
  int r0 = node0 + wv * 16 + hi * 4;
#pragma unroll
  for (int f = 0; f < 8; ++f) {
    float b = bl[f * 16 + lo];
#pragma unroll
    for (int r = 0; r < 4; ++r) acc[f][r] += b;
  }
#pragma unroll
  for (int r = 0; r < 4; ++r) {
    if (r0 + r >= n) {
#pragma unroll
      for (int f = 0; f < 8; ++f) acc[f][r] = 0.f;
    }
  }
  float ss[4] = {0.f, 0.f, 0.f, 0.f};
#pragma unroll
  for (int f = 0; f < 8; ++f)
#pragma unroll
    for (int r = 0; r < 4; ++r) ss[r] += acc[f][r] * acc[f][r];
#pragma unroll
  for (int m = 1; m <= 8; m <<= 1) {
#pragma unroll
    for (int r = 0; r < 4; ++r) ss[r] += __shfl_xor(ss[r], m, 64);
  }
#pragma unroll
  for (int r = 0; r < 4; ++r) {
    float inv = 1.0f / fmaxf(sqrtf(ss[r]), 1e-12f);
#pragma unroll
    for (int f = 0; f < 8; ++f) acc[f][r] *= inv;
  }
  float s1[8], s2[8];
#pragma unroll
  for (int f = 0; f < 8; ++f) { s1[f] = 0.f; s2[f] = 0.f; }
#pragma unroll
  for (int f = 0; f < 8; ++f) {
#pragma unroll
    for (int r = 0; r < 4; ++r) {
      float v = acc[f][r];
      s1[f] += v;
      s2[f] += v * v;
      if (r0 + r < n) hout[(size_t)(r0 + r) * DF + f * 16 + lo] = v;
    }
  }
#pragma unroll
  for (int f = 0; f < 8; ++f) {
    s1[f] += __shfl_xor(s1[f], 16, 64);
    s1[f] += __shfl_xor(s1[f], 32, 64);
    s2[f] += __shfl_xor(s2[f], 16, 64);
    s2[f] += __shfl_xor(s2[f], 32, 64);
  }
  __syncthreads();  // done with Abuf/Bbuf reads
  if (hi == 0) {
#pragma unroll
    for (int f = 0; f < 8; ++f) {
      red[wv * 256 + f * 16 + lo] = s1[f];
      red[wv * 256 + 128 + f * 16 + lo] = s2[f];
    }
  }
  __syncthreads();
  float v = red[tid] + red[256 + tid] + red[512 + tid] + red[768 + tid];
  pf[(size_t)blockIdx.x * 256 + tid] = v;
}

// ---- first-level partial reduction: 16 blocks x 256 feats (coalesced)
__global__ void k_reduce(const float* __restrict__ pf, float* __restrict__ pf2, int NB) {
  int g = blockIdx.x, t = threadIdx.x;
  int L = (NB + 15) / 16;
  int b0 = g * L, b1 = (b0 + L < NB) ? b0 + L : NB;
  float a = 0.f;
  for (int r = b0; r < b1; ++r) a += pf[(size_t)r * 256 + t];
  pf2[g * 256 + t] = a;
}

// ---- GraphNorm coefficients: out = ca*h + cb per feature
__global__ void k_coef(const float* __restrict__ pf2,
                       const float* __restrict__ gnw, const float* __restrict__ gnb,
                       const float* __restrict__ alpha, float* __restrict__ coef, int n) {
  int j = threadIdx.x;  // 0..127
  float s = 0.f, q = 0.f;
#pragma unroll
  for (int g = 0; g < 16; ++g) {
    s += pf2[g * 256 + j];
    q += pf2[g * 256 + 128 + j];
  }
  float invn = 1.0f / (float)n;
  float mean = s * invn;
  float m2 = q * invn;
  float a = alpha[j];
  float var = m2 - mean * mean * (2.0f * a - a * a);
  float ca = gnw[j] / sqrtf(var + 1e-5f);
  float cb = gnb[j] - ca * a * mean;
  coef[j] = ca;
  coef[DF + j] = cb;
}

// ---- affine + exact GELU + residual, in-place on d_out
__global__ void k_final(float* __restrict__ out, const float* __restrict__ x,
                        const float* __restrict__ coef, int total4) {
  int i = blockIdx.x * 256 + threadIdx.x;
  if (i >= total4) return;
  int cj = (i & 31) * 4;
  float4 h = ((const float4*)out)[i];
  float4 xv = ((const float4*)x)[i];
  float4 ca = *(const float4*)(coef + cj);
  float4 cb = *(const float4*)(coef + DF + cj);
  float4 o;
#define GEL(comp)                                                         \
  {                                                                       \
    float v = ca.comp * h.comp + cb.comp;                                 \
    float g = 0.5f * v * (1.0f + erff(v * 0.70710678118654752f));         \
    o.comp = g + xv.comp;                                                 \
  }
  GEL(x) GEL(y) GEL(z) GEL(w)
#undef GEL
  ((float4*)out)[i] = o;
}

extern "C" void kernel_launch(void* const* d_in, const int* in_sizes, int n_in,
                              void* d_out, int out_size, void* d_ws, size_t ws_size,
                              hipStream_t stream) {
  const float* x = (const float*)d_in[0];
  const int* ei = (const int*)d_in[1];
  // d_in[2] = batch (all zeros, unused)
  const float* Wl = (const float*)d_in[3];
  const float* bl = (const float*)d_in[4];
  const float* Wr = (const float*)d_in[5];
  const float* gnw = (const float*)d_in[6];
  const float* gnb = (const float*)d_in[7];
  const float* alpha = (const float*)d_in[8];
  int n = in_sizes[2];
  int E = in_sizes[1] / 2;
  int NBK = (n + 63) / 64;        // buckets == gemm blocks
  const int NBLK = 128;           // hist/scatter blocks
  int CE = (E + NBLK - 1) / NBLK;
  int CHK = (NBK + 255) / 256;    // <=16 for n<=262144
  float* out = (float*)d_out;
  (void)n_in; (void)out_size;

  char* ws = (char*)d_ws;
  size_t off = 0;
  auto carve = [&](size_t b) {
    char* p = ws + off;
    off = (off + b + 255) & ~(size_t)255;
    return p;
  };
  unsigned int* ebuf = (unsigned int*)carve((size_t)E * 4);
  unsigned int* hist = (unsigned int*)carve((size_t)NBLK * NBK * 4);
  unsigned int* base = (unsigned int*)carve((size_t)NBLK * NBK * 4);
  unsigned int* tot = (unsigned int*)carve((size_t)NBK * 4);
  unsigned int* bstart = (unsigned int*)carve((size_t)(NBK + 1) * 4);
  unsigned short* wbf = (unsigned short*)carve((size_t)DF * 256 * 2);
  float* coef = (float*)carve(256 * 4);
  float* pf = (float*)carve((size_t)NBK * 256 * 4);
  float* pf2 = (float*)carve(16 * 256 * 4);
  size_t need_bf = off + (size_t)n * DF * 2;
  int useBF = (ws_size >= need_bf) ? 1 : 0;
  unsigned int* xbf = (unsigned int*)carve((size_t)n * DF * 2);

  k_wcvt<<<(DF * 256) / 256, 256, 0, stream>>>(Wl, Wr, wbf);
  k_hist<<<NBLK, 256, 0, stream>>>(ei, hist, E, NBK, CE);
  k_btot<<<(NBK + 255) / 256, 256, 0, stream>>>(hist, tot, NBK, NBLK);
  k_scan<<<1, 256, 0, stream>>>(tot, bstart, NBK, CHK);
  k_base<<<(NBK + 255) / 256, 256, 0, stream>>>(hist, bstart, base, NBK, NBLK);
  k_scat<<<NBLK, 256, 0, stream>>>(ei, base, ebuf, E, NBK, CE);
  if (useBF) {
    k_xcvt<<<(n * 16 + 255) / 256, 256, 0, stream>>>(x, xbf, n * 16);
    k_gemm<1><<<NBK, 256, 0, stream>>>(ebuf, bstart, xbf, x, wbf, bl, out, pf, n);
  } else {
    k_gemm<0><<<NBK, 256, 0, stream>>>(ebuf, bstart, xbf, x, wbf, bl, out, pf, n);
  }
  k_reduce<<<16, 256, 0, stream>>>(pf, pf2, NBK);
  k_coef<<<1, DF, 0, stream>>>(pf2, gnw, gnb, alpha, coef, n);
  k_final<<<(n * 32 + 255) / 256, 256, 0, stream>>>(out, x, coef, n * 32);
}